// Round 1
// baseline (139.246 us; speedup 1.0000x reference)
//
#include <hip/hip_runtime.h>
#include <math.h>

// Encoder: x(B,T,N) -> LSTM gates (f-gate dead: c_prev=0) -> query=[h,c]
// -> s2 = query@w2 -> e[n] = sum_k tanh(x[n]*w1[k]+w1b[k]+s2[k])*v[k]
// -> softmax over n -> out = x*alpha.   B=64 T=128 N=U=128.
//
// Phase 1 (tiled, 16 rows/block): z-gates + s2, stores pre-scaled
//   c2C[row,k] = (s2[row,k] + w2b[k] + w1b[k]) * 2*log2(e)
// Phase 2 (1 row/block, 128 thr): the 134M-tanh reduction + softmax.
// v_bias omitted: softmax is shift-invariant.

#define BT   8192   // B*T rows
#define NF   128    // N == U == T
#define ROWS 16     // rows per phase-1 block

__device__ __forceinline__ float fast_rcp(float x)  { return __builtin_amdgcn_rcpf(x); }
__device__ __forceinline__ float fast_exp2(float x) { return __builtin_amdgcn_exp2f(x); }

#define K_C     2.8853900817779268f   /* 2*log2(e) */
#define K_LOG2E 1.4426950408889634f

// tanh(t) where tC = t * 2*log2(e):  sign(t) * (1 - 2/(1 + 2^|tC|))
__device__ __forceinline__ float tanh_from_scaled(float tC) {
    float e = fast_exp2(fabsf(tC));                 // exp(2|t|); inf-safe
    float r = fmaf(-2.f, fast_rcp(1.f + e), 1.f);
    return copysignf(r, tC);
}
__device__ __forceinline__ float tanh_fast(float t) { return tanh_from_scaled(t * K_C); }
__device__ __forceinline__ float sig_fast(float z) {
    return fast_rcp(1.f + fast_exp2(-K_LOG2E * z)); // 1/(1+e^-z)
}

// ---------------- Phase 1: rows-tiled gates + s2 ----------------
// grid 512, block 256 (4 waves). Thread t: u = t&127 (output col),
// rh = (t>>7)*8 (row group of 8). LDS: x tile 8KB + query tile 16KB.
__global__ __launch_bounds__(256) void phase1(
    const float* __restrict__ x,  const float* __restrict__ Wl,
    const float* __restrict__ bl, const float* __restrict__ w2,
    const float* __restrict__ b2, const float* __restrict__ b1,
    float* __restrict__ s2c)
{
    __shared__ __align__(16) float xs[ROWS][NF];
    __shared__ __align__(16) float qs[ROWS][2 * NF];
    const int t  = threadIdx.x;
    const int r0 = blockIdx.x * ROWS;

    #pragma unroll
    for (int i = t; i < ROWS * NF; i += 256)
        xs[i >> 7][i & 127] = x[r0 * NF + i];
    __syncthreads();

    const int u  = t & 127;
    const int rh = (t >> 7) * 8;

    // Stage B: z for gates i (col u), g (256+u), o (384+u); f-gate skipped.
    float ai[8], ag[8], ao[8];
    #pragma unroll
    for (int r = 0; r < 8; r++) { ai[r] = 0.f; ag[r] = 0.f; ao[r] = 0.f; }
    const float* wp = Wl + u;
    for (int j = 0; j < NF; j += 4) {
        float wi[4], wg[4], wo[4];
        #pragma unroll
        for (int jj = 0; jj < 4; jj++) {
            wi[jj] = wp[(j + jj) * 512];
            wg[jj] = wp[(j + jj) * 512 + 256];
            wo[jj] = wp[(j + jj) * 512 + 384];
        }
        #pragma unroll
        for (int r = 0; r < 8; r++) {
            const float4 xv = *(const float4*)&xs[rh + r][j];  // lds broadcast
            ai[r] = fmaf(xv.x, wi[0], ai[r]); ag[r] = fmaf(xv.x, wg[0], ag[r]); ao[r] = fmaf(xv.x, wo[0], ao[r]);
            ai[r] = fmaf(xv.y, wi[1], ai[r]); ag[r] = fmaf(xv.y, wg[1], ag[r]); ao[r] = fmaf(xv.y, wo[1], ao[r]);
            ai[r] = fmaf(xv.z, wi[2], ai[r]); ag[r] = fmaf(xv.z, wg[2], ag[r]); ao[r] = fmaf(xv.z, wo[2], ao[r]);
            ai[r] = fmaf(xv.w, wi[3], ai[r]); ag[r] = fmaf(xv.w, wg[3], ag[r]); ao[r] = fmaf(xv.w, wo[3], ao[r]);
        }
    }
    const float bi = bl[u], bg = bl[256 + u], bo = bl[384 + u];
    #pragma unroll
    for (int r = 0; r < 8; r++) {
        const float c = sig_fast(ai[r] + bi) * tanh_fast(ag[r] + bg);
        const float h = sig_fast(ao[r] + bo) * tanh_fast(c);
        qs[rh + r][u]      = h;   // query = [h, c]
        qs[rh + r][NF + u] = c;
    }
    __syncthreads();

    // Stage C: s2[row, u] = sum_j query[row, j] * w2[j, u]
    float acc[8];
    #pragma unroll
    for (int r = 0; r < 8; r++) acc[r] = 0.f;
    const float* w2p = w2 + u;
    for (int j = 0; j < 2 * NF; j += 4) {
        float wv[4];
        #pragma unroll
        for (int jj = 0; jj < 4; jj++) wv[jj] = w2p[(j + jj) * NF];
        #pragma unroll
        for (int r = 0; r < 8; r++) {
            const float4 qv = *(const float4*)&qs[rh + r][j];
            acc[r] = fmaf(qv.x, wv[0], acc[r]);
            acc[r] = fmaf(qv.y, wv[1], acc[r]);
            acc[r] = fmaf(qv.z, wv[2], acc[r]);
            acc[r] = fmaf(qv.w, wv[3], acc[r]);
        }
    }
    const float bias = (b2[u] + b1[u]) * K_C;   // pre-scale for phase 2
    #pragma unroll
    for (int r = 0; r < 8; r++)
        s2c[(r0 + rh + r) * NF + u] = fmaf(acc[r], K_C, bias);
}

// ---------------- Phase 2: e[n] = sum_k tanh(...)·v[k], softmax, out ----
// grid 8192 (one (b,t) row), block 128 (2 waves), thread n in [0,128).
__global__ __launch_bounds__(128) void phase2(
    const float* __restrict__ x,  const float* __restrict__ w1,
    const float* __restrict__ v,  const float* __restrict__ s2c,
    float* __restrict__ out)
{
    __shared__ __align__(16) float w1Cs[NF];
    __shared__ __align__(16) float vs[NF];
    __shared__ __align__(16) float c2s[NF];
    __shared__ float red[4];
    const int n   = threadIdx.x;
    const int row = blockIdx.x;

    w1Cs[n] = w1[n] * K_C;
    vs[n]   = v[n];
    c2s[n]  = s2c[row * NF + n];      // may alias out: read before write
    const float xn = x[row * NF + n];
    __syncthreads();

    float acc = 0.f;
    #pragma unroll 8
    for (int k = 0; k < NF; k += 4) {
        const float4 w4 = *(const float4*)&w1Cs[k];  // lds broadcast reads
        const float4 c4 = *(const float4*)&c2s[k];
        const float4 v4 = *(const float4*)&vs[k];
        acc = fmaf(tanh_from_scaled(fmaf(xn, w4.x, c4.x)), v4.x, acc);
        acc = fmaf(tanh_from_scaled(fmaf(xn, w4.y, c4.y)), v4.y, acc);
        acc = fmaf(tanh_from_scaled(fmaf(xn, w4.z, c4.z)), v4.z, acc);
        acc = fmaf(tanh_from_scaled(fmaf(xn, w4.w, c4.w)), v4.w, acc);
    }

    // softmax over the 128 n's (2 waves): butterfly + LDS combine
    float m = acc;
    #pragma unroll
    for (int off = 1; off < 64; off <<= 1) m = fmaxf(m, __shfl_xor(m, off, 64));
    if ((n & 63) == 0) red[n >> 6] = m;
    __syncthreads();
    m = fmaxf(red[0], red[1]);
    const float p = fast_exp2(K_LOG2E * (acc - m));
    float s = p;
    #pragma unroll
    for (int off = 1; off < 64; off <<= 1) s += __shfl_xor(s, off, 64);
    if ((n & 63) == 0) red[2 + (n >> 6)] = s;
    __syncthreads();
    s = red[2] + red[3];

    out[row * NF + n] = xn * p * fast_rcp(s);
}

extern "C" void kernel_launch(void* const* d_in, const int* in_sizes, int n_in,
                              void* d_out, int out_size, void* d_ws, size_t ws_size,
                              hipStream_t stream) {
    const float* x  = (const float*)d_in[0];
    // d_in[1]=hidden_state, d_in[2]=cell_state: ignored by reference semantics
    const float* Wl = (const float*)d_in[3];   // (128, 512)
    const float* bl = (const float*)d_in[4];   // (512,)
    const float* w1 = (const float*)d_in[5];   // (1, 128)
    const float* b1 = (const float*)d_in[6];   // (128,)
    const float* w2 = (const float*)d_in[7];   // (256, 128)
    const float* b2 = (const float*)d_in[8];   // (128,)
    const float* v  = (const float*)d_in[9];   // (128, 1)
    // d_in[10]=v_bias: softmax-invariant, omitted. d_in[11]=n: unused.
    float* out = (float*)d_out;

    // 4 MB intermediate; fall back to d_out if workspace is too small
    // (phase 2 reads its s2c row into LDS before overwriting that row).
    float* s2c = (ws_size >= (size_t)BT * NF * sizeof(float)) ? (float*)d_ws : out;

    phase1<<<BT / ROWS, 256, 0, stream>>>(x, Wl, bl, w2, b2, b1, s2c);
    phase2<<<BT, 128, 0, stream>>>(x, w1, v, s2c, out);
}

// Round 2
// 134.869 us; speedup vs baseline: 1.0325x; 1.0325x over previous
//
#include <hip/hip_runtime.h>
#include <math.h>

// Encoder: x(B,T,N) -> LSTM gates (f-gate dead: c_prev=0) -> query=[h,c]
// -> s2 = query@w2 -> e[n] = sum_k tanh(x[n]*w1[k]+w1b[k]+s2[k])*v[k]
// -> softmax over n -> out = x*alpha.   B=64 T=128 N=U=T=128.
//
// Phase 1 (16 rows/block, 512 thr): gates + s2, stores pre-scaled
//   c2C[row,k] = (s2[row,k] + w2b[k] + w1b[k]) * 2*log2(e)
// Phase 2 (1 row/block, 128 thr): e[n] = F(x[n]) where
//   F(xi) = sum_k tanh(xi*w1[k] + c[k]) * v[k]  is one smooth scalar
//   function per row -> evaluate exactly at 32 nodes over the row's
//   [min,max], Catmull-Rom cubic interp per n (err ~1e-5 << threshold).
// v_bias omitted: softmax is shift-invariant.

#define BT   8192   // B*T rows
#define NF   128    // N == U == T
#define ROWS 16     // rows per phase-1 block

__device__ __forceinline__ float fast_rcp(float x)  { return __builtin_amdgcn_rcpf(x); }
__device__ __forceinline__ float fast_exp2(float x) { return __builtin_amdgcn_exp2f(x); }

#define K_C     2.8853900817779268f   /* 2*log2(e) */
#define K_LOG2E 1.4426950408889634f

// tanh(t) where tC = t * 2*log2(e):  sign(t) * (1 - 2/(1 + 2^|tC|))
__device__ __forceinline__ float tanh_from_scaled(float tC) {
    float e = fast_exp2(fabsf(tC));                 // exp(2|t|); inf-safe
    float r = fmaf(-2.f, fast_rcp(1.f + e), 1.f);
    return copysignf(r, tC);
}
__device__ __forceinline__ float tanh_fast(float t) { return tanh_from_scaled(t * K_C); }
__device__ __forceinline__ float sig_fast(float z) {
    return fast_rcp(1.f + fast_exp2(-K_LOG2E * z)); // 1/(1+e^-z)
}

// ---------------- Phase 1: rows-tiled gates + s2 ----------------
// grid 512, block 512 (8 waves -> 2 blocks/CU = 16 waves/CU).
// Thread t: u = t&127 (output col), quarter (t>>7) owns 4 rows.
__global__ __launch_bounds__(512, 4) void phase1(
    const float* __restrict__ x,  const float* __restrict__ Wl,
    const float* __restrict__ bl, const float* __restrict__ w2,
    const float* __restrict__ b2, const float* __restrict__ b1,
    float* __restrict__ s2c)
{
    __shared__ __align__(16) float xs[ROWS][NF];       // 8 KB
    __shared__ __align__(16) float qs[ROWS][2 * NF];   // 16 KB
    const int t  = threadIdx.x;
    const int r0 = blockIdx.x * ROWS;

    for (int i = t; i < ROWS * NF; i += 512)
        xs[i >> 7][i & 127] = x[r0 * NF + i];
    __syncthreads();

    const int u  = t & 127;
    const int rh = (t >> 7) * 4;    // 0,4,8,12

    // Stage B: z for gates i (col u), g (256+u), o (384+u); f-gate dead.
    float ai[4] = {0,0,0,0}, ag[4] = {0,0,0,0}, ao[4] = {0,0,0,0};
    const float* wp = Wl + u;
    #pragma unroll 4
    for (int j = 0; j < NF; j += 4) {
        float wi[4], wg[4], wo[4];
        #pragma unroll
        for (int jj = 0; jj < 4; jj++) {
            wi[jj] = wp[(j + jj) * 512];
            wg[jj] = wp[(j + jj) * 512 + 256];
            wo[jj] = wp[(j + jj) * 512 + 384];
        }
        #pragma unroll
        for (int r = 0; r < 4; r++) {
            const float4 xv = *(const float4*)&xs[rh + r][j];  // lds broadcast
            ai[r] = fmaf(xv.x, wi[0], ai[r]); ag[r] = fmaf(xv.x, wg[0], ag[r]); ao[r] = fmaf(xv.x, wo[0], ao[r]);
            ai[r] = fmaf(xv.y, wi[1], ai[r]); ag[r] = fmaf(xv.y, wg[1], ag[r]); ao[r] = fmaf(xv.y, wo[1], ao[r]);
            ai[r] = fmaf(xv.z, wi[2], ai[r]); ag[r] = fmaf(xv.z, wg[2], ag[r]); ao[r] = fmaf(xv.z, wo[2], ao[r]);
            ai[r] = fmaf(xv.w, wi[3], ai[r]); ag[r] = fmaf(xv.w, wg[3], ag[r]); ao[r] = fmaf(xv.w, wo[3], ao[r]);
        }
    }
    const float bi = bl[u], bg = bl[256 + u], bo = bl[384 + u];
    #pragma unroll
    for (int r = 0; r < 4; r++) {
        const float c = sig_fast(ai[r] + bi) * tanh_fast(ag[r] + bg);
        const float h = sig_fast(ao[r] + bo) * tanh_fast(c);
        qs[rh + r][u]      = h;   // query = [h, c]
        qs[rh + r][NF + u] = c;
    }
    __syncthreads();

    // Stage C: s2[row, u] = sum_j query[row, j] * w2[j, u]
    float acc[4] = {0,0,0,0};
    const float* w2p = w2 + u;
    #pragma unroll 4
    for (int j = 0; j < 2 * NF; j += 4) {
        float wv[4];
        #pragma unroll
        for (int jj = 0; jj < 4; jj++) wv[jj] = w2p[(j + jj) * NF];
        #pragma unroll
        for (int r = 0; r < 4; r++) {
            const float4 qv = *(const float4*)&qs[rh + r][j];
            acc[r] = fmaf(qv.x, wv[0], acc[r]);
            acc[r] = fmaf(qv.y, wv[1], acc[r]);
            acc[r] = fmaf(qv.z, wv[2], acc[r]);
            acc[r] = fmaf(qv.w, wv[3], acc[r]);
        }
    }
    const float bias = (b2[u] + b1[u]) * K_C;   // pre-scale for phase 2
    #pragma unroll
    for (int r = 0; r < 4; r++)
        s2c[(r0 + rh + r) * NF + u] = fmaf(acc[r], K_C, bias);
}

// ---------------- Phase 2: spline-accelerated e[n] + softmax ----------
// grid 8192 (one (b,t) row), block 128 (2 waves), thread n in [0,128).
__global__ __launch_bounds__(128) void phase2(
    const float* __restrict__ x,  const float* __restrict__ w1,
    const float* __restrict__ v,  const float* __restrict__ s2c,
    float* __restrict__ out)
{
    __shared__ __align__(16) float w1Cs[NF];
    __shared__ __align__(16) float vs[NF];
    __shared__ __align__(16) float c2s[NF];
    __shared__ __align__(16) float part[4][32];
    __shared__ float Ftab[32];
    __shared__ float red[4];
    const int t   = threadIdx.x;
    const int row = blockIdx.x;

    w1Cs[t] = w1[t] * K_C;
    vs[t]   = v[t];
    c2s[t]  = s2c[row * NF + t];      // may alias out: read before write
    const float xn = x[row * NF + t];

    // block min/max of x over the row
    float mn = xn, mx = xn;
    #pragma unroll
    for (int off = 1; off < 64; off <<= 1) {
        mn = fminf(mn, __shfl_xor(mn, off, 64));
        mx = fmaxf(mx, __shfl_xor(mx, off, 64));
    }
    if ((t & 63) == 0) { red[t >> 6] = mn; red[2 + (t >> 6)] = mx; }
    __syncthreads();
    mn = fminf(red[0], red[1]);
    mx = fmaxf(red[2], red[3]);
    const float span = mx - mn;
    const float h    = span * (1.f / 29.f);
    const float invh = span > 1e-12f ? 29.f / span : 0.f;  // degenerate row -> F[1]

    // Node eval: node m = t&31 at xi = mn + (m-1)*h; k-quarter q = t>>5.
    // Per wave, LDS reads hit only 2 distinct addresses (2-way = free).
    const int   m  = t & 31, q = t >> 5;
    const float xi = fmaf((float)(m - 1), h, mn);
    float acc = 0.f;
    const int k0 = q * 32;
    #pragma unroll
    for (int j = 0; j < 32; j += 4) {
        const float4 w4 = *(const float4*)&w1Cs[k0 + j];
        const float4 c4 = *(const float4*)&c2s[k0 + j];
        const float4 v4 = *(const float4*)&vs[k0 + j];
        acc = fmaf(tanh_from_scaled(fmaf(xi, w4.x, c4.x)), v4.x, acc);
        acc = fmaf(tanh_from_scaled(fmaf(xi, w4.y, c4.y)), v4.y, acc);
        acc = fmaf(tanh_from_scaled(fmaf(xi, w4.z, c4.z)), v4.z, acc);
        acc = fmaf(tanh_from_scaled(fmaf(xi, w4.w, c4.w)), v4.w, acc);
    }
    part[q][m] = acc;
    __syncthreads();
    if (t < 32) Ftab[t] = (part[0][t] + part[1][t]) + (part[2][t] + part[3][t]);
    __syncthreads();

    // Per-n Catmull-Rom interp: s in [1,30]; i clamped so i-1..i+2 in [0,31].
    float sN = fmaf(xn - mn, invh, 1.0f);
    int   i  = (int)sN;
    i = i < 1 ? 1 : (i > 29 ? 29 : i);
    const float f  = sN - (float)i;
    const float F0 = Ftab[i - 1], F1 = Ftab[i], F2 = Ftab[i + 1], F3 = Ftab[i + 2];
    const float e  = F1 + 0.5f * f * ((F2 - F0)
                   + f * ((2.f * F0 - 5.f * F1 + 4.f * F2 - F3)
                   + f * (3.f * (F1 - F2) + F3 - F0)));

    // softmax over the 128 n's (2 waves)
    float mval = e;
    #pragma unroll
    for (int off = 1; off < 64; off <<= 1) mval = fmaxf(mval, __shfl_xor(mval, off, 64));
    if ((t & 63) == 0) red[t >> 6] = mval;
    __syncthreads();
    mval = fmaxf(red[0], red[1]);
    const float p = fast_exp2(K_LOG2E * (e - mval));
    float ssum = p;
    #pragma unroll
    for (int off = 1; off < 64; off <<= 1) ssum += __shfl_xor(ssum, off, 64);
    if ((t & 63) == 0) red[2 + (t >> 6)] = ssum;
    __syncthreads();
    ssum = red[2] + red[3];

    out[row * NF + t] = xn * p * fast_rcp(ssum);
}

extern "C" void kernel_launch(void* const* d_in, const int* in_sizes, int n_in,
                              void* d_out, int out_size, void* d_ws, size_t ws_size,
                              hipStream_t stream) {
    const float* x  = (const float*)d_in[0];
    // d_in[1]=hidden_state, d_in[2]=cell_state: ignored by reference semantics
    const float* Wl = (const float*)d_in[3];   // (128, 512)
    const float* bl = (const float*)d_in[4];   // (512,)
    const float* w1 = (const float*)d_in[5];   // (1, 128)
    const float* b1 = (const float*)d_in[6];   // (128,)
    const float* w2 = (const float*)d_in[7];   // (256, 128)
    const float* b2 = (const float*)d_in[8];   // (128,)
    const float* v  = (const float*)d_in[9];   // (128, 1)
    // d_in[10]=v_bias: softmax-invariant, omitted. d_in[11]=n: unused.
    float* out = (float*)d_out;

    // 4 MB intermediate; fall back to d_out if workspace is too small
    // (phase 2 reads its s2c row into LDS before overwriting that row).
    float* s2c = (ws_size >= (size_t)BT * NF * sizeof(float)) ? (float*)d_ws : out;

    phase1<<<BT / ROWS, 512, 0, stream>>>(x, Wl, bl, w2, b2, b1, s2c);
    phase2<<<BT, 128, 0, stream>>>(x, w1, v, s2c, out);
}

// Round 3
// 104.681 us; speedup vs baseline: 1.3302x; 1.2884x over previous
//
#include <hip/hip_runtime.h>
#include <math.h>

// Encoder: x(B,T,N) -> LSTM gates (f-gate dead: c_prev=0) -> query=[h,c]
// -> s2 = query@w2 -> e[n] = sum_k tanh(x[n]*w1[k]+w1b[k]+s2[k])*v[k]
// -> softmax over n -> out = x*alpha.   B=64 T=128 N=U=T=128.
//
// prep: Wl(i,g,o cols) + w2 -> bf16 MFMA-fragment order in ws (160 KB).
// g1  : 32 rows/block, 4 waves. GEMM1 via mfma_f32_16x16x32_bf16 (B1 frags
//       staged LDS in 4 k-phases), gates in C-layout regs, query -> LDS in
//       A-frag order, GEMM2 (B2 frags from L2) -> s2c pre-scaled:
//       s2c[row,k] = (s2 + w2b[k] + w1b[k]) * 2*log2(e).
// phase2: per row, e[n] = F(x[n]) via 32-node eval + Catmull-Rom interp.
// v_bias omitted: softmax is shift-invariant.
//
// Verified gfx950 16x16x32 bf16 layouts (m89/m91/m120):
//   A-frag: lane l holds A[m=l&15][k=(l>>4)*8+j], j=0..7
//   B-frag: lane l holds B[k=(l>>4)*8+j][n=l&15]
//   C/D   : reg r  is  C[row=(l>>4)*4+r][col=l&15]

typedef __attribute__((ext_vector_type(8))) short short8;
typedef __attribute__((ext_vector_type(4))) float f32x4;

#define BT 8192
#define NF 128
#define K_C     2.8853900817779268f   /* 2*log2(e) */
#define K_LOG2E 1.4426950408889634f

__device__ __forceinline__ float fast_rcp(float x)  { return __builtin_amdgcn_rcpf(x); }
__device__ __forceinline__ float fast_exp2(float x) { return __builtin_amdgcn_exp2f(x); }

__device__ __forceinline__ float tanh_from_scaled(float tC) {
    float e = fast_exp2(fabsf(tC));
    float r = fmaf(-2.f, fast_rcp(1.f + e), 1.f);
    return copysignf(r, tC);
}
__device__ __forceinline__ float tanh_fast(float t) { return tanh_from_scaled(t * K_C); }
__device__ __forceinline__ float sig_fast(float z) {
    return fast_rcp(1.f + fast_exp2(-K_LOG2E * z));
}
// f32 -> bf16 RNE (inputs finite; no NaN handling needed)
__device__ __forceinline__ unsigned short f2bf(float f) {
    unsigned u = __float_as_uint(f);
    return (unsigned short)((u + 0x7fffu + ((u >> 16) & 1u)) >> 16);
}

// ---------------- prep: weights -> bf16 frag order in ws ----------------
// ws layout (ushort units): B1f[96 frag-sets][512] then B2f[64][512].
// B1 frag-set fs = nt*4+kk, nt = g*8+jt (g: i/g/o, jt: u16-tile).
__global__ __launch_bounds__(64) void prep(const float* __restrict__ Wl,
                                           const float* __restrict__ w2,
                                           unsigned short* __restrict__ wsB) {
    const int lane = threadIdx.x;
    const int n16 = lane & 15, q = lane >> 4;
    const int b = blockIdx.x;
    if (b < 96) {
        const int nt = b >> 2, kk = b & 3;
        const int g = nt >> 3, jt = nt & 7;
        const int goff = (g == 0) ? 0 : (g == 1 ? 256 : 384);
        const int col = goff + jt * 16 + n16;
        unsigned short* d = wsB + b * 512 + lane * 8;
        #pragma unroll
        for (int j = 0; j < 8; j++)
            d[j] = f2bf(Wl[(kk * 32 + q * 8 + j) * 512 + col]);
    } else {
        const int fs = b - 96;
        const int nt2 = fs >> 3, kk2 = fs & 7;
        const int col = nt2 * 16 + n16;
        unsigned short* d = wsB + 49152 + fs * 512 + lane * 8;
        #pragma unroll
        for (int j = 0; j < 8; j++)
            d[j] = f2bf(w2[(kk2 * 32 + q * 8 + j) * 128 + col]);
    }
}

// ---------------- g1: MFMA GEMM1 + gates + MFMA GEMM2 ----------------
// grid 256, block 256 (4 waves). Wave w: m-tile mt=w&1 (16 rows),
// n-half js=w>>1 (u16-tiles js*4..js*4+3).
__global__ __launch_bounds__(256, 3) void g1(
    const float* __restrict__ x,  const unsigned short* __restrict__ wsB,
    const float* __restrict__ bl, const float* __restrict__ b2,
    const float* __restrict__ b1, float* __restrict__ s2c)
{
    __shared__ unsigned short B1s[24 * 512];   // 24 KB: one k-phase of B1 frags
    __shared__ unsigned short Qf[2 * 4096];    // 16 KB: query A-frags, 2 m-tiles
    const int t    = threadIdx.x;
    const int lane = t & 63, w = t >> 6;
    const int n16  = lane & 15, q = lane >> 4;
    const int mt   = w & 1, js = w >> 1;
    const int rowbase = blockIdx.x * 32 + mt * 16;

    // A-frags from x (f32 -> bf16 in-register)
    short8 af[4];
    const float* xrow = x + (rowbase + n16) * 128 + q * 8;
    #pragma unroll
    for (int kk = 0; kk < 4; kk++) {
        const float4 v0 = *(const float4*)(xrow + kk * 32);
        const float4 v1 = *(const float4*)(xrow + kk * 32 + 4);
        short8 a;
        a[0] = f2bf(v0.x); a[1] = f2bf(v0.y); a[2] = f2bf(v0.z); a[3] = f2bf(v0.w);
        a[4] = f2bf(v1.x); a[5] = f2bf(v1.y); a[6] = f2bf(v1.z); a[7] = f2bf(v1.w);
        af[kk] = a;
    }

    f32x4 acc[4][3];
    #pragma unroll
    for (int tr = 0; tr < 4; tr++)
        #pragma unroll
        for (int g = 0; g < 3; g++) acc[tr][g] = (f32x4)(0.f);

    // GEMM1 in 4 k-phases; B1 frag-sets (nt, kk=ph) staged to LDS each phase
    const uint4* Bg = (const uint4*)wsB;
    for (int ph = 0; ph < 4; ph++) {
        __syncthreads();                       // protect previous phase reads
        for (int i = t; i < 1536; i += 256) {
            const int nt = i >> 6;
            ((uint4*)B1s)[i] = Bg[(nt * 4 + ph) * 64 + (i & 63)];
        }
        __syncthreads();
        #pragma unroll
        for (int tr = 0; tr < 4; tr++) {
            const int jt = js * 4 + tr;
            #pragma unroll
            for (int g = 0; g < 3; g++) {
                const short8 bf = *(const short8*)&B1s[(g * 8 + jt) * 512 + lane * 8];
                acc[tr][g] = __builtin_amdgcn_mfma_f32_16x16x32_bf16(
                    af[ph], bf, acc[tr][g], 0, 0, 0);
            }
        }
    }

    // Gates (C-layout regs) -> query bf16 into Qf in GEMM2-A-frag order.
    // Element (row m2=q*4+r, kq): kk2=kq>>5, q2=(kq&31)>>3, j2=kq&7,
    // lane2=m2+16*q2, idx = mt*4096 + kk2*512 + lane2*8 + j2.
    #pragma unroll
    for (int tr = 0; tr < 4; tr++) {
        const int jt = js * 4 + tr;
        const int u  = jt * 16 + n16;
        const float bi = bl[u], bg = bl[256 + u], bo = bl[384 + u];
        const int kqh = u, kqc = 128 + u;
        const int baseh = mt * 4096 + (kqh >> 5) * 512 + ((kqh & 31) >> 3) * 128
                        + q * 32 + (kqh & 7);
        const int basec = mt * 4096 + (kqc >> 5) * 512 + ((kqc & 31) >> 3) * 128
                        + q * 32 + (kqc & 7);
        #pragma unroll
        for (int r = 0; r < 4; r++) {
            const float c = sig_fast(acc[tr][0][r] + bi) * tanh_fast(acc[tr][1][r] + bg);
            const float h = sig_fast(acc[tr][2][r] + bo) * tanh_fast(c);
            Qf[baseh + r * 8] = f2bf(h);
            Qf[basec + r * 8] = f2bf(c);
        }
    }
    __syncthreads();

    // GEMM2: A = query (own m-tile), B2 frags from L2; wave covers nt2 js*4..+3
    short8 a2[8];
    #pragma unroll
    for (int kk2 = 0; kk2 < 8; kk2++)
        a2[kk2] = *(const short8*)&Qf[mt * 4096 + kk2 * 512 + lane * 8];

    const short8* B2g = (const short8*)(wsB + 49152);
    #pragma unroll
    for (int tr2 = 0; tr2 < 4; tr2++) {
        const int nt2 = js * 4 + tr2;
        f32x4 acc2 = (f32x4)(0.f);
        #pragma unroll
        for (int kk2 = 0; kk2 < 8; kk2++) {
            const short8 bf = B2g[(nt2 * 8 + kk2) * 64 + lane];
            acc2 = __builtin_amdgcn_mfma_f32_16x16x32_bf16(a2[kk2], bf, acc2, 0, 0, 0);
        }
        const int u2 = nt2 * 16 + n16;
        const float bias2 = (b2[u2] + b1[u2]) * K_C;   // pre-scale for phase 2
        #pragma unroll
        for (int r = 0; r < 4; r++)
            s2c[(rowbase + q * 4 + r) * 128 + u2] = fmaf(acc2[r], K_C, bias2);
    }
}

// ---------------- phase2: spline-accelerated e[n] + softmax (unchanged) ----
__global__ __launch_bounds__(128) void phase2(
    const float* __restrict__ x,  const float* __restrict__ w1,
    const float* __restrict__ v,  const float* __restrict__ s2c,
    float* __restrict__ out)
{
    __shared__ __align__(16) float w1Cs[NF];
    __shared__ __align__(16) float vs[NF];
    __shared__ __align__(16) float c2s[NF];
    __shared__ __align__(16) float part[4][32];
    __shared__ float Ftab[32];
    __shared__ float red[4];
    const int t   = threadIdx.x;
    const int row = blockIdx.x;

    w1Cs[t] = w1[t] * K_C;
    vs[t]   = v[t];
    c2s[t]  = s2c[row * NF + t];      // may alias out: read before write
    const float xn = x[row * NF + t];

    float mn = xn, mx = xn;
    #pragma unroll
    for (int off = 1; off < 64; off <<= 1) {
        mn = fminf(mn, __shfl_xor(mn, off, 64));
        mx = fmaxf(mx, __shfl_xor(mx, off, 64));
    }
    if ((t & 63) == 0) { red[t >> 6] = mn; red[2 + (t >> 6)] = mx; }
    __syncthreads();
    mn = fminf(red[0], red[1]);
    mx = fmaxf(red[2], red[3]);
    const float span = mx - mn;
    const float h    = span * (1.f / 29.f);
    const float invh = span > 1e-12f ? 29.f / span : 0.f;

    const int   m  = t & 31, qq = t >> 5;
    const float xi = fmaf((float)(m - 1), h, mn);
    float acc = 0.f;
    const int k0 = qq * 32;
    #pragma unroll
    for (int j = 0; j < 32; j += 4) {
        const float4 w4 = *(const float4*)&w1Cs[k0 + j];
        const float4 c4 = *(const float4*)&c2s[k0 + j];
        const float4 v4 = *(const float4*)&vs[k0 + j];
        acc = fmaf(tanh_from_scaled(fmaf(xi, w4.x, c4.x)), v4.x, acc);
        acc = fmaf(tanh_from_scaled(fmaf(xi, w4.y, c4.y)), v4.y, acc);
        acc = fmaf(tanh_from_scaled(fmaf(xi, w4.z, c4.z)), v4.z, acc);
        acc = fmaf(tanh_from_scaled(fmaf(xi, w4.w, c4.w)), v4.w, acc);
    }
    part[qq][m] = acc;
    __syncthreads();
    if (t < 32) Ftab[t] = (part[0][t] + part[1][t]) + (part[2][t] + part[3][t]);
    __syncthreads();

    float sN = fmaf(xn - mn, invh, 1.0f);
    int   i  = (int)sN;
    i = i < 1 ? 1 : (i > 29 ? 29 : i);
    const float f  = sN - (float)i;
    const float F0 = Ftab[i - 1], F1 = Ftab[i], F2 = Ftab[i + 1], F3 = Ftab[i + 2];
    const float e  = F1 + 0.5f * f * ((F2 - F0)
                   + f * ((2.f * F0 - 5.f * F1 + 4.f * F2 - F3)
                   + f * (3.f * (F1 - F2) + F3 - F0)));

    float mval = e;
    #pragma unroll
    for (int off = 1; off < 64; off <<= 1) mval = fmaxf(mval, __shfl_xor(mval, off, 64));
    if ((t & 63) == 0) red[t >> 6] = mval;
    __syncthreads();
    mval = fmaxf(red[0], red[1]);
    const float p = fast_exp2(K_LOG2E * (e - mval));
    float ssum = p;
    #pragma unroll
    for (int off = 1; off < 64; off <<= 1) ssum += __shfl_xor(ssum, off, 64);
    if ((t & 63) == 0) red[2 + (t >> 6)] = ssum;
    __syncthreads();
    ssum = red[2] + red[3];

    out[row * NF + t] = xn * p * fast_rcp(ssum);
}

extern "C" void kernel_launch(void* const* d_in, const int* in_sizes, int n_in,
                              void* d_out, int out_size, void* d_ws, size_t ws_size,
                              hipStream_t stream) {
    const float* x  = (const float*)d_in[0];
    // d_in[1]=hidden_state, d_in[2]=cell_state: ignored by reference semantics
    const float* Wl = (const float*)d_in[3];   // (128, 512)
    const float* bl = (const float*)d_in[4];   // (512,)
    const float* w1 = (const float*)d_in[5];   // (1, 128)
    const float* b1 = (const float*)d_in[6];   // (128,)
    const float* w2 = (const float*)d_in[7];   // (256, 128)
    const float* b2 = (const float*)d_in[8];   // (128,)
    const float* v  = (const float*)d_in[9];   // (128, 1)
    // d_in[10]=v_bias: softmax-invariant, omitted. d_in[11]=n: unused.
    float* out = (float*)d_out;

    unsigned short* wsB = (unsigned short*)d_ws;      // 160 KB frag weights
    const size_t wreq = 160 * 1024;
    // s2c: 4 MB after the weights if it fits, else alias d_out (phase2 reads
    // its s2c row into LDS before overwriting that row).
    float* s2c = (ws_size >= wreq + (size_t)BT * NF * sizeof(float))
               ? (float*)((char*)d_ws + wreq) : out;

    prep<<<160, 64, 0, stream>>>(Wl, w2, wsB);
    g1<<<256, 256, 0, stream>>>(x, wsB, bl, b2, b1, s2c);
    phase2<<<BT, 128, 0, stream>>>(x, w1, v, s2c, out);
}

// Round 4
// 94.537 us; speedup vs baseline: 1.4729x; 1.1073x over previous
//
#include <hip/hip_runtime.h>
#include <math.h>

// Encoder: x(B,T,N) -> LSTM gates (f-gate dead: c_prev=0) -> query=[h,c]
// -> s2 = query@w2 -> e[n] = sum_k tanh(x[n]*w1[k]+w1b[k]+s2[k])*v[k]
// -> softmax over n -> out = x*alpha.   B=64 T=128 N=U=T=128.
//
// prep: Wl(i,g,o cols) + w2 -> bf16 MFMA-fragment order in ws (160 KB).
// enc : ONE fused kernel, 16 rows/block, 512 blocks (2 blocks/CU):
//       GEMM1 (mfma 16x16x32 bf16, B frags straight from L2) -> gates in
//       C-layout regs -> query bf16 -> LDS A-frag order -> GEMM2 -> s2c
//       scaled into LDS (never global) -> per-row 32-node tanh table ->
//       Catmull-Rom interp -> softmax -> out.  3 barriers total.
// v_bias omitted: softmax is shift-invariant.
//
// Verified gfx950 16x16x32 bf16 layouts (m89/m91/m120):
//   A-frag: lane l holds A[m=l&15][k=(l>>4)*8+j], j=0..7
//   B-frag: lane l holds B[k=(l>>4)*8+j][n=l&15]
//   C/D   : reg r  is  C[row=(l>>4)*4+r][col=l&15]

typedef __attribute__((ext_vector_type(8))) short short8;
typedef __attribute__((ext_vector_type(4))) float f32x4;

#define BT 8192
#define NF 128
#define K_C     2.8853900817779268f   /* 2*log2(e) */
#define K_LOG2E 1.4426950408889634f

__device__ __forceinline__ float fast_rcp(float x)  { return __builtin_amdgcn_rcpf(x); }
__device__ __forceinline__ float fast_exp2(float x) { return __builtin_amdgcn_exp2f(x); }

// tanh(t) with tC = 2*log2(e)*t: 1 - 2/(1+2^tC); exp2 saturation handles +/-inf
__device__ __forceinline__ float tanh_nc(float tC) {
    return fmaf(-2.f, fast_rcp(1.f + fast_exp2(tC)), 1.f);
}
__device__ __forceinline__ float tanh_fast(float t) { return tanh_nc(t * K_C); }
__device__ __forceinline__ float sig_fast(float z) {
    return fast_rcp(1.f + fast_exp2(-K_LOG2E * z));
}
// f32 -> bf16 RNE (inputs finite)
__device__ __forceinline__ unsigned short f2bf(float f) {
    unsigned u = __float_as_uint(f);
    return (unsigned short)((u + 0x7fffu + ((u >> 16) & 1u)) >> 16);
}

// ---------------- prep: weights -> bf16 frag order in ws ----------------
// ws layout (ushort units): B1f[96 frag-sets][512] then B2f[64][512].
// B1 frag-set fs = nt*4+kk, nt = g*8+jt (g: i/g/o, jt: u16-tile).
__global__ __launch_bounds__(64) void prep(const float* __restrict__ Wl,
                                           const float* __restrict__ w2,
                                           unsigned short* __restrict__ wsB) {
    const int lane = threadIdx.x;
    const int n16 = lane & 15, q = lane >> 4;
    const int b = blockIdx.x;
    if (b < 96) {
        const int nt = b >> 2, kk = b & 3;
        const int g = nt >> 3, jt = nt & 7;
        const int goff = (g == 0) ? 0 : (g == 1 ? 256 : 384);
        const int col = goff + jt * 16 + n16;
        unsigned short* d = wsB + b * 512 + lane * 8;
        #pragma unroll
        for (int j = 0; j < 8; j++)
            d[j] = f2bf(Wl[(kk * 32 + q * 8 + j) * 512 + col]);
    } else {
        const int fs = b - 96;
        const int nt2 = fs >> 3, kk2 = fs & 7;
        const int col = nt2 * 16 + n16;
        unsigned short* d = wsB + 49152 + fs * 512 + lane * 8;
        #pragma unroll
        for (int j = 0; j < 8; j++)
            d[j] = f2bf(w2[(kk2 * 32 + q * 8 + j) * 128 + col]);
    }
}

// ---------------- enc: fused GEMM1 + gates + GEMM2 + spline + softmax ----
// grid 512, block 256 (4 waves, 2 blocks/CU). Wave w owns u16-tiles
// {2w, 2w+1} in both GEMMs; block owns 16 rows (one MFMA m-tile).
__global__ __launch_bounds__(256, 2) void enc(
    const float* __restrict__ x,  const unsigned short* __restrict__ wsB,
    const float* __restrict__ bl, const float* __restrict__ b2,
    const float* __restrict__ b1, const float* __restrict__ w1,
    const float* __restrict__ v,  float* __restrict__ out)
{
    __shared__ __align__(16) float xs[16][NF];        // 8 KB: x rows
    __shared__ unsigned short Qf[8 * 512];            // 8 KB: query A-frags
    __shared__ __align__(16) float c2[16][NF];        // 8 KB: scaled s2c
    __shared__ __align__(16) float w1Cs[NF], vs[NF];  // 1 KB
    __shared__ float Ftab[16][32];                    // 2 KB
    __shared__ float rowMn[16], rowMx[16];

    const int t    = threadIdx.x;
    const int lane = t & 63, w = t >> 6;
    const int n16  = lane & 15, q = lane >> 4;
    const int rowbase = blockIdx.x * 16;

    // stage xs (coalesced float4) + small vectors
    for (int i = t; i < 512; i += 256)
        ((float4*)xs)[i] = ((const float4*)(x + rowbase * NF))[i];
    if (t < NF) { w1Cs[t] = w1[t] * K_C; vs[t] = v[t]; }

    // A-frags straight from global x (f32 -> bf16 in-register)
    short8 af[4];
    const float* xrow = x + (rowbase + n16) * NF + q * 8;
    #pragma unroll
    for (int kk = 0; kk < 4; kk++) {
        const float4 v0 = *(const float4*)(xrow + kk * 32);
        const float4 v1 = *(const float4*)(xrow + kk * 32 + 4);
        short8 a;
        a[0] = f2bf(v0.x); a[1] = f2bf(v0.y); a[2] = f2bf(v0.z); a[3] = f2bf(v0.w);
        a[4] = f2bf(v1.x); a[5] = f2bf(v1.y); a[6] = f2bf(v1.z); a[7] = f2bf(v1.w);
        af[kk] = a;
    }

    // GEMM1: wave covers jt in {2w, 2w+1} for all 3 live gates; B1 from L2
    f32x4 acc[2][3];
    #pragma unroll
    for (int j2 = 0; j2 < 2; j2++)
        #pragma unroll
        for (int g = 0; g < 3; g++) acc[j2][g] = (f32x4)(0.f);
    const short8* B1g = (const short8*)wsB;
    #pragma unroll
    for (int kk = 0; kk < 4; kk++)
        #pragma unroll
        for (int j2 = 0; j2 < 2; j2++) {
            const int jt = w * 2 + j2;
            #pragma unroll
            for (int g = 0; g < 3; g++) {
                const short8 bf = B1g[(((g * 8 + jt) * 4) + kk) * 64 + lane];
                acc[j2][g] = __builtin_amdgcn_mfma_f32_16x16x32_bf16(
                    af[kk], bf, acc[j2][g], 0, 0, 0);
            }
        }

    // Gates -> query bf16 into Qf in GEMM2 A-frag order (K=256: h then c).
    // Element (m2=q*4+r, kq): idx = (kq>>5)*512 + ((kq&31)>>3)*128 + q*32 + (kq&7) + r*8
    #pragma unroll
    for (int j2 = 0; j2 < 2; j2++) {
        const int jt = w * 2 + j2;
        const int u  = jt * 16 + n16;
        const float bi = bl[u], bg = bl[256 + u], bo = bl[384 + u];
        const int kqh = u, kqc = NF + u;
        const int baseh = (kqh >> 5) * 512 + ((kqh & 31) >> 3) * 128 + q * 32 + (kqh & 7);
        const int basec = (kqc >> 5) * 512 + ((kqc & 31) >> 3) * 128 + q * 32 + (kqc & 7);
        #pragma unroll
        for (int r = 0; r < 4; r++) {
            const float c = sig_fast(acc[j2][0][r] + bi) * tanh_fast(acc[j2][1][r] + bg);
            const float h = sig_fast(acc[j2][2][r] + bo) * tanh_fast(c);
            Qf[baseh + r * 8] = f2bf(h);
            Qf[basec + r * 8] = f2bf(c);
        }
    }
    __syncthreads();   // barrier A: Qf (and xs, w1Cs, vs) ready

    // GEMM2: A = query frags from LDS, B2 frags from L2
    short8 a2[8];
    #pragma unroll
    for (int kk2 = 0; kk2 < 8; kk2++)
        a2[kk2] = *(const short8*)&Qf[kk2 * 512 + lane * 8];
    const short8* B2g = (const short8*)(wsB + 49152);
    #pragma unroll
    for (int j2 = 0; j2 < 2; j2++) {
        const int nt2 = w * 2 + j2;
        f32x4 acc2 = (f32x4)(0.f);
        #pragma unroll
        for (int kk2 = 0; kk2 < 8; kk2++) {
            const short8 bf = B2g[(nt2 * 8 + kk2) * 64 + lane];
            acc2 = __builtin_amdgcn_mfma_f32_16x16x32_bf16(a2[kk2], bf, acc2, 0, 0, 0);
        }
        const int u2 = nt2 * 16 + n16;
        const float bias2 = (b2[u2] + b1[u2]) * K_C;   // pre-scaled for spline
        #pragma unroll
        for (int r = 0; r < 4; r++)
            c2[q * 4 + r][u2] = fmaf(acc2[r], K_C, bias2);
    }

    // row min/max of x: wave w reduces rows 4w..4w+3
    #pragma unroll
    for (int r4 = 0; r4 < 4; r4++) {
        const int row = w * 4 + r4;
        float a = xs[row][lane], b = xs[row][64 + lane];
        float mn = fminf(a, b), mx = fmaxf(a, b);
        #pragma unroll
        for (int off = 1; off < 64; off <<= 1) {
            mn = fminf(mn, __shfl_xor(mn, off, 64));
            mx = fmaxf(mx, __shfl_xor(mx, off, 64));
        }
        if (lane == 0) { rowMn[row] = mn; rowMx[row] = mx; }
    }
    __syncthreads();   // barrier B: c2 + rowMn/Mx ready

    // Node eval: thread does 2 full (row, node) k=128 sums -> Ftab direct.
    // Per wave only 2 distinct c2 rows -> LDS float4 broadcast reads.
    #pragma unroll
    for (int p = 0; p < 2; p++) {
        const int row = p * 8 + (t >> 5);
        const int m   = t & 31;
        const float mn = rowMn[row];
        const float h  = (rowMx[row] - mn) * (1.f / 29.f);
        const float xi = fmaf((float)(m - 1), h, mn);
        float accF = 0.f;
        #pragma unroll 4
        for (int k = 0; k < NF; k += 4) {
            const float4 w4 = *(const float4*)&w1Cs[k];
            const float4 c4 = *(const float4*)&c2[row][k];
            const float4 v4 = *(const float4*)&vs[k];
            accF = fmaf(tanh_nc(fmaf(xi, w4.x, c4.x)), v4.x, accF);
            accF = fmaf(tanh_nc(fmaf(xi, w4.y, c4.y)), v4.y, accF);
            accF = fmaf(tanh_nc(fmaf(xi, w4.z, c4.z)), v4.z, accF);
            accF = fmaf(tanh_nc(fmaf(xi, w4.w, c4.w)), v4.w, accF);
        }
        Ftab[row][m] = accF;
    }
    __syncthreads();   // barrier C: Ftab ready

    // Interp + softmax + store: 16 threads/row, 8 consecutive n each.
    {
        const int row = t >> 4;
        const int n0  = (t & 15) * 8;
        const float mn   = rowMn[row];
        const float span = rowMx[row] - mn;
        const float invh = span > 1e-12f ? 29.f / span : 0.f;
        float xv[8], e8[8];
        *(float4*)&xv[0] = *(const float4*)&xs[row][n0];
        *(float4*)&xv[4] = *(const float4*)&xs[row][n0 + 4];
        #pragma unroll
        for (int i = 0; i < 8; i++) {
            const float sN = fmaf(xv[i] - mn, invh, 1.0f);
            int ii = (int)sN;
            ii = ii < 1 ? 1 : (ii > 29 ? 29 : ii);
            const float f  = sN - (float)ii;
            const float F0 = Ftab[row][ii - 1], F1 = Ftab[row][ii];
            const float F2 = Ftab[row][ii + 1], F3 = Ftab[row][ii + 2];
            e8[i] = F1 + 0.5f * f * ((F2 - F0)
                  + f * ((2.f * F0 - 5.f * F1 + 4.f * F2 - F3)
                  + f * (3.f * (F1 - F2) + F3 - F0)));
        }
        float mval = e8[0];
        #pragma unroll
        for (int i = 1; i < 8; i++) mval = fmaxf(mval, e8[i]);
        #pragma unroll
        for (int off = 1; off < 16; off <<= 1) mval = fmaxf(mval, __shfl_xor(mval, off, 64));
        float ssum = 0.f;
        #pragma unroll
        for (int i = 0; i < 8; i++) { e8[i] = fast_exp2(K_LOG2E * (e8[i] - mval)); ssum += e8[i]; }
        #pragma unroll
        for (int off = 1; off < 16; off <<= 1) ssum += __shfl_xor(ssum, off, 64);
        const float rs = fast_rcp(ssum);
        float4 o0, o1;
        o0.x = xv[0] * e8[0] * rs; o0.y = xv[1] * e8[1] * rs;
        o0.z = xv[2] * e8[2] * rs; o0.w = xv[3] * e8[3] * rs;
        o1.x = xv[4] * e8[4] * rs; o1.y = xv[5] * e8[5] * rs;
        o1.z = xv[6] * e8[6] * rs; o1.w = xv[7] * e8[7] * rs;
        float* op = out + (rowbase + row) * NF + n0;
        *(float4*)op       = o0;
        *(float4*)(op + 4) = o1;
    }
}

extern "C" void kernel_launch(void* const* d_in, const int* in_sizes, int n_in,
                              void* d_out, int out_size, void* d_ws, size_t ws_size,
                              hipStream_t stream) {
    const float* x  = (const float*)d_in[0];
    // d_in[1]=hidden_state, d_in[2]=cell_state: ignored by reference semantics
    const float* Wl = (const float*)d_in[3];   // (128, 512)
    const float* bl = (const float*)d_in[4];   // (512,)
    const float* w1 = (const float*)d_in[5];   // (1, 128)
    const float* b1 = (const float*)d_in[6];   // (128,)
    const float* w2 = (const float*)d_in[7];   // (256, 128)
    const float* b2 = (const float*)d_in[8];   // (128,)
    const float* v  = (const float*)d_in[9];   // (128, 1)
    // d_in[10]=v_bias: softmax-invariant, omitted. d_in[11]=n: unused.
    float* out = (float*)d_out;
    unsigned short* wsB = (unsigned short*)d_ws;   // 160 KB bf16 frag weights

    prep<<<160, 64, 0, stream>>>(Wl, w2, wsB);
    enc<<<BT / 16, 256, 0, stream>>>(x, wsB, bl, b2, b1, w1, v, out);
}

// Round 5
// 87.931 us; speedup vs baseline: 1.5836x; 1.0751x over previous
//
#include <hip/hip_runtime.h>
#include <math.h>

// Encoder: x(B,T,N) -> LSTM gates (f-gate dead: c_prev=0) -> query=[h,c]
// -> s2 = query@w2 -> e[n] = sum_k tanh(x[n]*w1[k]+w1b[k]+s2[k])*v[k]
// -> softmax over n -> out = x*alpha.   B=64 T=128 N=U=T=128.
//
// prep: Wl(i,g,o cols) + w2 -> bf16 MFMA-fragment order in ws (160 KB).
// enc : fused, 16 rows/block, 512 thr (8 waves, 2 blocks/CU = 4 waves/SIMD):
//       GEMM1 (mfma 16x16x32 bf16, 1 u16-tile/wave, B frags from L2) ->
//       gates -> query bf16 -> LDS A-frag order -> GEMM2 -> c2 in LDS ->
//       16-node tanh table (k split across thread pairs) -> Catmull-Rom
//       interp -> softmax -> out.  4 barriers.
// v_bias omitted: softmax is shift-invariant.
//
// Verified gfx950 16x16x32 bf16 layouts (m89/m91/m120):
//   A-frag: lane l holds A[m=l&15][k=(l>>4)*8+j], j=0..7
//   B-frag: lane l holds B[k=(l>>4)*8+j][n=l&15]
//   C/D   : reg r  is  C[row=(l>>4)*4+r][col=l&15]

typedef __attribute__((ext_vector_type(8))) short short8;
typedef __attribute__((ext_vector_type(4))) float f32x4;

#define BT 8192
#define NF 128
#define XP 132          /* xs row pad: +4 floats -> 2-way banks on A-frag reads */
#define K_C     2.8853900817779268f   /* 2*log2(e) */
#define K_LOG2E 1.4426950408889634f

__device__ __forceinline__ float fast_rcp(float x)  { return __builtin_amdgcn_rcpf(x); }
__device__ __forceinline__ float fast_exp2(float x) { return __builtin_amdgcn_exp2f(x); }

// tanh(t) with tC = 2*log2(e)*t: 1 - 2/(1+2^tC); exp2 saturation handles +/-inf
__device__ __forceinline__ float tanh_nc(float tC) {
    return fmaf(-2.f, fast_rcp(1.f + fast_exp2(tC)), 1.f);
}
__device__ __forceinline__ float tanh_fast(float t) { return tanh_nc(t * K_C); }
__device__ __forceinline__ float sig_fast(float z) {
    return fast_rcp(1.f + fast_exp2(-K_LOG2E * z));
}
// f32 -> bf16 RNE (inputs finite)
__device__ __forceinline__ unsigned short f2bf(float f) {
    unsigned u = __float_as_uint(f);
    return (unsigned short)((u + 0x7fffu + ((u >> 16) & 1u)) >> 16);
}

// ---------------- prep: weights -> bf16 frag order in ws ----------------
// ws layout (ushort units): B1f[96 frag-sets][512] then B2f[64][512].
// B1 frag-set fs = nt*4+kk, nt = g*8+jt (g: i/g/o, jt: u16-tile).
__global__ __launch_bounds__(64) void prep(const float* __restrict__ Wl,
                                           const float* __restrict__ w2,
                                           unsigned short* __restrict__ wsB) {
    const int lane = threadIdx.x;
    const int n16 = lane & 15, q = lane >> 4;
    const int b = blockIdx.x;
    if (b < 96) {
        const int nt = b >> 2, kk = b & 3;
        const int g = nt >> 3, jt = nt & 7;
        const int goff = (g == 0) ? 0 : (g == 1 ? 256 : 384);
        const int col = goff + jt * 16 + n16;
        unsigned short* d = wsB + b * 512 + lane * 8;
        #pragma unroll
        for (int j = 0; j < 8; j++)
            d[j] = f2bf(Wl[(kk * 32 + q * 8 + j) * 512 + col]);
    } else {
        const int fs = b - 96;
        const int nt2 = fs >> 3, kk2 = fs & 7;
        const int col = nt2 * 16 + n16;
        unsigned short* d = wsB + 49152 + fs * 512 + lane * 8;
        #pragma unroll
        for (int j = 0; j < 8; j++)
            d[j] = f2bf(w2[(kk2 * 32 + q * 8 + j) * 128 + col]);
    }
}

// ---------------- enc: fused GEMM1 + gates + GEMM2 + spline + softmax ----
// grid 512, block 512 (8 waves). Wave w owns u16-tile w in both GEMMs;
// block owns 16 rows (one MFMA m-tile).
__global__ __launch_bounds__(512, 4) void enc(
    const float* __restrict__ x,  const unsigned short* __restrict__ wsB,
    const float* __restrict__ bl, const float* __restrict__ b2,
    const float* __restrict__ b1, const float* __restrict__ w1,
    const float* __restrict__ v,  float* __restrict__ out)
{
    __shared__ __align__(16) float xs[16][XP];        // 8.25 KB, padded
    __shared__ unsigned short Qf[8 * 512];            // 8 KB: query A-frags
    __shared__ __align__(16) float c2[16][NF];        // 8 KB: scaled s2c
    __shared__ __align__(16) float w1Cs[NF], vs[NF];  // 1 KB
    __shared__ float Ftab[16][16];                    // 1 KB
    __shared__ float rowMn[16], rowMx[16];

    const int t    = threadIdx.x;
    const int lane = t & 63, w = t >> 6;
    const int n16  = lane & 15, q = lane >> 4;
    const int rowbase = blockIdx.x * 16;

    // stage xs: one coalesced float4 per thread
    {
        const int row = t >> 5, c4 = (t & 31) * 4;
        *(float4*)&xs[row][c4] = *(const float4*)(x + (rowbase + row) * NF + c4);
    }
    if (t < NF) { w1Cs[t] = w1[t] * K_C; vs[t] = v[t]; }
    __syncthreads();   // barrier 0: xs ready

    // row min/max: 32 threads per row, 4 elems each
    {
        const int row = t >> 5, c4 = (t & 31) * 4;
        const float4 xv = *(const float4*)&xs[row][c4];
        float mn = fminf(fminf(xv.x, xv.y), fminf(xv.z, xv.w));
        float mx = fmaxf(fmaxf(xv.x, xv.y), fmaxf(xv.z, xv.w));
        #pragma unroll
        for (int off = 1; off < 32; off <<= 1) {
            mn = fminf(mn, __shfl_xor(mn, off, 64));
            mx = fmaxf(mx, __shfl_xor(mx, off, 64));
        }
        if ((t & 31) == 0) { rowMn[row] = mn; rowMx[row] = mx; }
    }

    // A-frags from LDS xs (f32 -> bf16 in-register)
    short8 af[4];
    #pragma unroll
    for (int kk = 0; kk < 4; kk++) {
        const float4 v0 = *(const float4*)&xs[n16][kk * 32 + q * 8];
        const float4 v1 = *(const float4*)&xs[n16][kk * 32 + q * 8 + 4];
        short8 a;
        a[0] = f2bf(v0.x); a[1] = f2bf(v0.y); a[2] = f2bf(v0.z); a[3] = f2bf(v0.w);
        a[4] = f2bf(v1.x); a[5] = f2bf(v1.y); a[6] = f2bf(v1.z); a[7] = f2bf(v1.w);
        af[kk] = a;
    }

    // GEMM1: wave covers u16-tile jt = w, all 3 live gates; B1 frags from L2
    f32x4 acc[3];
    #pragma unroll
    for (int g = 0; g < 3; g++) acc[g] = (f32x4)(0.f);
    const short8* B1g = (const short8*)wsB;
    #pragma unroll
    for (int kk = 0; kk < 4; kk++)
        #pragma unroll
        for (int g = 0; g < 3; g++) {
            const short8 bf = B1g[(((g * 8 + w) * 4) + kk) * 64 + lane];
            acc[g] = __builtin_amdgcn_mfma_f32_16x16x32_bf16(af[kk], bf, acc[g], 0, 0, 0);
        }

    // Gates -> query bf16 into Qf in GEMM2 A-frag order (K=256: h then c).
    // Element (m2=q*4+r, kq): idx = (kq>>5)*512 + ((kq&31)>>3)*128 + q*32 + (kq&7) + r*8
    const int u = w * 16 + n16;
    {
        const float bi = bl[u], bg = bl[256 + u], bo = bl[384 + u];
        const int kqh = u, kqc = NF + u;
        const int baseh = (kqh >> 5) * 512 + ((kqh & 31) >> 3) * 128 + q * 32 + (kqh & 7);
        const int basec = (kqc >> 5) * 512 + ((kqc & 31) >> 3) * 128 + q * 32 + (kqc & 7);
        #pragma unroll
        for (int r = 0; r < 4; r++) {
            const float c = sig_fast(acc[0][r] + bi) * tanh_fast(acc[1][r] + bg);
            const float h = sig_fast(acc[2][r] + bo) * tanh_fast(c);
            Qf[baseh + r * 8] = f2bf(h);
            Qf[basec + r * 8] = f2bf(c);
        }
    }
    __syncthreads();   // barrier A: Qf ready

    // GEMM2: A = query frags from LDS (contiguous b128), B2 frags from L2
    {
        short8 a2[8];
        #pragma unroll
        for (int kk2 = 0; kk2 < 8; kk2++)
            a2[kk2] = *(const short8*)&Qf[kk2 * 512 + lane * 8];
        const short8* B2g = (const short8*)(wsB + 49152);
        f32x4 acc2 = (f32x4)(0.f);
        #pragma unroll
        for (int kk2 = 0; kk2 < 8; kk2++) {
            const short8 bf = B2g[(w * 8 + kk2) * 64 + lane];
            acc2 = __builtin_amdgcn_mfma_f32_16x16x32_bf16(a2[kk2], bf, acc2, 0, 0, 0);
        }
        const float bias2 = (b2[u] + b1[u]) * K_C;   // pre-scaled for spline
        #pragma unroll
        for (int r = 0; r < 4; r++)
            c2[q * 4 + r][u] = fmaf(acc2[r], K_C, bias2);
    }
    __syncthreads();   // barrier B: c2 + rowMn/Mx ready

    // Node eval: 16 nodes/row, k split across thread pairs (64 tanh each).
    // Thread: row = t>>5, node m = (t>>1)&15, k-half = t&1.
    // c2/w1Cs/vs reads: 2 distinct addrs per 32-lane group -> 2-way = free.
    {
        const int row = t >> 5;
        const int m   = (t >> 1) & 15;
        const int k0  = (t & 1) * 64;
        const float mn = rowMn[row];
        const float h  = (rowMx[row] - mn) * (1.f / 13.f);
        const float xi = fmaf((float)(m - 1), h, mn);
        float accF = 0.f;
        #pragma unroll 4
        for (int k = k0; k < k0 + 64; k += 4) {
            const float4 w4 = *(const float4*)&w1Cs[k];
            const float4 c4 = *(const float4*)&c2[row][k];
            const float4 v4 = *(const float4*)&vs[k];
            accF = fmaf(tanh_nc(fmaf(xi, w4.x, c4.x)), v4.x, accF);
            accF = fmaf(tanh_nc(fmaf(xi, w4.y, c4.y)), v4.y, accF);
            accF = fmaf(tanh_nc(fmaf(xi, w4.z, c4.z)), v4.z, accF);
            accF = fmaf(tanh_nc(fmaf(xi, w4.w, c4.w)), v4.w, accF);
        }
        accF += __shfl_xor(accF, 1, 64);   // combine k-halves
        if ((t & 1) == 0) Ftab[row][m] = accF;
    }
    __syncthreads();   // barrier C: Ftab ready

    // Interp + softmax + store: 32 threads/row, 4 consecutive n each.
    {
        const int row = t >> 5;
        const int n0  = (t & 31) * 4;
        const float mn   = rowMn[row];
        const float span = rowMx[row] - mn;
        const float invh = span > 1e-12f ? 13.f / span : 0.f;
        const float4 xv = *(const float4*)&xs[row][n0];
        float xa[4] = {xv.x, xv.y, xv.z, xv.w};
        float e4[4];
        #pragma unroll
        for (int i = 0; i < 4; i++) {
            const float sN = fmaf(xa[i] - mn, invh, 1.0f);
            int ii = (int)sN;
            ii = ii < 1 ? 1 : (ii > 13 ? 13 : ii);
            const float f  = sN - (float)ii;
            const float F0 = Ftab[row][ii - 1], F1 = Ftab[row][ii];
            const float F2 = Ftab[row][ii + 1], F3 = Ftab[row][ii + 2];
            e4[i] = F1 + 0.5f * f * ((F2 - F0)
                  + f * ((2.f * F0 - 5.f * F1 + 4.f * F2 - F3)
                  + f * (3.f * (F1 - F2) + F3 - F0)));
        }
        float mval = fmaxf(fmaxf(e4[0], e4[1]), fmaxf(e4[2], e4[3]));
        #pragma unroll
        for (int off = 1; off < 32; off <<= 1)
            mval = fmaxf(mval, __shfl_xor(mval, off, 64));
        float ssum = 0.f;
        #pragma unroll
        for (int i = 0; i < 4; i++) {
            e4[i] = fast_exp2(K_LOG2E * (e4[i] - mval));
            ssum += e4[i];
        }
        #pragma unroll
        for (int off = 1; off < 32; off <<= 1)
            ssum += __shfl_xor(ssum, off, 64);
        const float rs = fast_rcp(ssum);
        float4 o;
        o.x = xa[0] * e4[0] * rs; o.y = xa[1] * e4[1] * rs;
        o.z = xa[2] * e4[2] * rs; o.w = xa[3] * e4[3] * rs;
        *(float4*)(out + (rowbase + row) * NF + n0) = o;
    }
}

extern "C" void kernel_launch(void* const* d_in, const int* in_sizes, int n_in,
                              void* d_out, int out_size, void* d_ws, size_t ws_size,
                              hipStream_t stream) {
    const float* x  = (const float*)d_in[0];
    // d_in[1]=hidden_state, d_in[2]=cell_state: ignored by reference semantics
    const float* Wl = (const float*)d_in[3];   // (128, 512)
    const float* bl = (const float*)d_in[4];   // (512,)
    const float* w1 = (const float*)d_in[5];   // (1, 128)
    const float* b1 = (const float*)d_in[6];   // (128,)
    const float* w2 = (const float*)d_in[7];   // (256, 128)
    const float* b2 = (const float*)d_in[8];   // (128,)
    const float* v  = (const float*)d_in[9];   // (128, 1)
    // d_in[10]=v_bias: softmax-invariant, omitted. d_in[11]=n: unused.
    float* out = (float*)d_out;
    unsigned short* wsB = (unsigned short*)d_ws;   // 160 KB bf16 frag weights

    prep<<<160, 64, 0, stream>>>(Wl, w2, wsB);
    enc<<<BT / 16, 512, 0, stream>>>(x, wsB, bl, b2, b1, w1, v, out);
}